// Round 6
// baseline (110.549 us; speedup 1.0000x reference)
//
#include <hip/hip_runtime.h>

#define NE 8
#define HD 128
#define NPTS 65536
#define TM 64   // points per block

typedef __bf16 bf16x8 __attribute__((ext_vector_type(8)));
typedef __bf16 bf16x4 __attribute__((ext_vector_type(4)));
typedef float f32x4 __attribute__((ext_vector_type(4)));

__device__ __forceinline__ unsigned int f2bf(float f) {
    unsigned int u = __float_as_uint(f);
    u += 0x7FFFu + ((u >> 16) & 1u);   // RNE
    return u >> 16;
}

// XOR swizzle on 256B rows
__device__ __forceinline__ unsigned int swz(int row, int byte_in_row) {
    return (unsigned int)((row * 256 + byte_in_row) ^ ((row & 7) << 4));
}

// LDS-only barrier: drains ds ops but leaves global (vmcnt) loads in flight.
__device__ __forceinline__ void bar_lds() {
    asm volatile("s_waitcnt lgkmcnt(0)\ns_barrier" ::: "memory");
}

template<int KB0, int KB1>
__device__ __forceinline__ void loadA128(const unsigned short* __restrict__ Ag,
                                         bf16x8 (&a)[2][4], int tc, int lr, int lg) {
#pragma unroll
    for (int ca = 0; ca < 2; ++ca)
#pragma unroll
        for (int kb = KB0; kb < KB1; ++kb)
            a[ca][kb] = *(const bf16x8*)(Ag + (tc + ca * 16 + lr) * HD + kb * 32 + lg * 8);
}

__device__ __forceinline__ void loadA32(const unsigned short* __restrict__ Ag,
                                        bf16x8 (&a)[2], int tc, int lr, int lg) {
#pragma unroll
    for (int ca = 0; ca < 2; ++ca)
        a[ca] = *(const bf16x8*)(Ag + (tc + ca * 16 + lr) * 32 + lg * 8);
}

// MFMA core over LDS B (swizzled)
template<int NKB>
__device__ __forceinline__ void gemm_core(const bf16x8 (&a)[2][4], const char* Bb,
                                          f32x4 (&acc)[2][4], int lr, int lg) {
#pragma unroll
    for (int kb = 0; kb < NKB; ++kb) {
        bf16x8 b[4];
#pragma unroll
        for (int nb = 0; nb < 4; ++nb)
            b[nb] = *(const bf16x8*)(Bb + swz(nb * 16 + lr, kb * 64 + lg * 16));
#pragma unroll
        for (int ca = 0; ca < 2; ++ca)
#pragma unroll
            for (int nb = 0; nb < 4; ++nb)
                acc[ca][nb] = __builtin_amdgcn_mfma_f32_16x16x32_bf16(a[ca][kb], b[nb], acc[ca][nb], 0, 0, 0);
    }
}

// bias + relu + bf16-pack + swizzled LDS store (bias preloaded in regs)
__device__ __forceinline__ void epi_store(const f32x4 (&acc)[2][4], char* Db,
                                          const float4 (&bs)[2], int tc, int lr, int lg) {
#pragma unroll
    for (int ca = 0; ca < 2; ++ca) {
        int c0 = tc + ca * 16 + lg * 4;
#pragma unroll
        for (int nb = 0; nb < 4; ++nb) {
            int r = nb * 16 + lr;
            bf16x4 pk;
            pk[0] = (__bf16)fmaxf(acc[ca][nb][0] + bs[ca].x, 0.f);
            pk[1] = (__bf16)fmaxf(acc[ca][nb][1] + bs[ca].y, 0.f);
            pk[2] = (__bf16)fmaxf(acc[ca][nb][2] + bs[ca].z, 0.f);
            pk[3] = (__bf16)fmaxf(acc[ca][nb][3] + bs[ca].w, 0.f);
            *(bf16x4*)(Db + swz(r, c0 * 2)) = pk;
        }
    }
}

// Prep: fp32 -> bf16 weights. W0 padded K:3->32 with zeros.
__global__ void prep_kernel(const float* __restrict__ W0,
                            const float* __restrict__ W1,
                            const float* __restrict__ W2,
                            unsigned int* __restrict__ W1b,
                            unsigned int* __restrict__ W2b,
                            unsigned int* __restrict__ W0p) {
    int i = blockIdx.x * 256 + threadIdx.x;  // 0..65535
    float2 v = *(const float2*)(W1 + 2 * i);
    W1b[i] = f2bf(v.x) | (f2bf(v.y) << 16);
    float2 u = *(const float2*)(W2 + 2 * i);
    W2b[i] = f2bf(u.x) | (f2bf(u.y) << 16);
    if (i < NE * HD * 16) {
        int row = i >> 4;
        int kk = (i & 15) * 2;
        float a = (kk < 3) ? W0[row * 3 + kk] : 0.f;
        float b = (kk + 1 < 3) ? W0[row * 3 + kk + 1] : 0.f;
        W0p[i] = f2bf(a) | (f2bf(b) << 16);
    }
}

#define XPS 40   // Xp row stride in shorts (80 B)

__global__ __launch_bounds__(256, 4) void moe_main(
    const float* __restrict__ coords,
    const float* __restrict__ b0, const float* __restrict__ b1,
    const float* __restrict__ b2,
    const float* __restrict__ Wo, const float* __restrict__ bo,
    const unsigned short* __restrict__ W0p,
    const unsigned short* __restrict__ W1b,
    const unsigned short* __restrict__ W2b,
    float* __restrict__ out) {
    __shared__ __align__(16) unsigned short hA[TM * HD];   // 16 KB
    __shared__ __align__(16) unsigned short hB[TM * HD];   // 16 KB
    __shared__ __align__(16) unsigned short Xp[TM * XPS];  // 5 KB
    __shared__ __align__(16) float part[4 * TM];           // 1 KB per-wave dot partials

    const int tid = threadIdx.x;
    const int lane = tid & 63;
    const int w = tid >> 6;
    const int lr = lane & 15;
    const int lg = lane >> 4;
    const int tc = w * 32;
    const int row0 = blockIdx.x * TM;

    if (tid < TM) {
        unsigned int* rowp = (unsigned int*)(Xp + tid * XPS);
        float c0 = coords[(row0 + tid) * 3 + 0];
        float c1 = coords[(row0 + tid) * 3 + 1];
        float c2 = coords[(row0 + tid) * 3 + 2];
        rowp[0] = f2bf(c0) | (f2bf(c1) << 16);
        rowp[1] = f2bf(c2);
#pragma unroll
        for (int i = 2; i < XPS / 2; ++i) rowp[i] = 0;
    }
    bar_lds();

    // ---- loop-invariant X B-fragments -> registers ----
    bf16x8 xb[4];
#pragma unroll
    for (int nb = 0; nb < 4; ++nb)
        xb[nb] = *(const bf16x8*)(Xp + (nb * 16 + lr) * XPS + lg * 8);

    bf16x8 a0[2], a1[2][4], a2[2][4];
    loadA32(W0p, a0, tc, lr, lg);
    loadA128<0, 2>(W1b, a1, tc, lr, lg);

    // ---- prologue: L0(e=0) -> hA ----
    {
        float4 bs0[2];
#pragma unroll
        for (int ca = 0; ca < 2; ++ca) bs0[ca] = *(const float4*)(b0 + tc + ca * 16 + lg * 4);
        f32x4 acc0[2][4];
#pragma unroll
        for (int ca = 0; ca < 2; ++ca)
#pragma unroll
            for (int nb = 0; nb < 4; ++nb) {
                acc0[ca][nb] = (f32x4){0.f, 0.f, 0.f, 0.f};
                acc0[ca][nb] = __builtin_amdgcn_mfma_f32_16x16x32_bf16(a0[ca], xb[nb], acc0[ca][nb], 0, 0, 0);
            }
        loadA32(W0p + 1 * HD * 32, a0, tc, lr, lg);   // W0(e=1)
        epi_store(acc0, (char*)hA, bs0, tc, lr, lg);
    }
    bar_lds();

    float bmax = -3.0e38f;

    for (int e = 0; e < NE; ++e) {
        const unsigned short* W2e = W2b + e * HD * HD;
        const int e1 = (e < NE - 1) ? e + 1 : e;
        const int e2 = (e < NE - 2) ? e + 2 : e1;

        // ================= P1: L1(e): hA -> hB =================
        float4 bs1[2];
#pragma unroll
        for (int ca = 0; ca < 2; ++ca) bs1[ca] = *(const float4*)(b1 + e * HD + tc + ca * 16 + lg * 4);
        loadA128<2, 4>(W1b + e * HD * HD, a1, tc, lr, lg);
        f32x4 acc[2][4];
#pragma unroll
        for (int ca = 0; ca < 2; ++ca)
#pragma unroll
            for (int nb = 0; nb < 4; ++nb) acc[ca][nb] = (f32x4){0.f, 0.f, 0.f, 0.f};
        gemm_core<4>(a1, (const char*)hA, acc, lr, lg);
        loadA128<0, 2>(W2e, a2, tc, lr, lg);
        epi_store(acc, (char*)hB, bs1, tc, lr, lg);
        bar_lds();

        // ================= P2: L2(e)+dot, then L0(e+1) -> hA =================
        float4 bs2[2], wo[2], bs0[2];
#pragma unroll
        for (int ca = 0; ca < 2; ++ca) {
            int c0 = tc + ca * 16 + lg * 4;
            bs2[ca] = *(const float4*)(b2 + e * HD + c0);
            wo[ca] = *(const float4*)(Wo + e * HD + c0);
            bs0[ca] = *(const float4*)(b0 + e1 * HD + c0);
        }
        loadA128<2, 4>(W2e, a2, tc, lr, lg);
#pragma unroll
        for (int ca = 0; ca < 2; ++ca)
#pragma unroll
            for (int nb = 0; nb < 4; ++nb) acc[ca][nb] = (f32x4){0.f, 0.f, 0.f, 0.f};
        gemm_core<4>(a2, (const char*)hB, acc, lr, lg);

        // fused output dot
        {
            float s[4] = {0.f, 0.f, 0.f, 0.f};
#pragma unroll
            for (int ca = 0; ca < 2; ++ca)
#pragma unroll
                for (int nb = 0; nb < 4; ++nb) {
                    float v0 = fmaxf(acc[ca][nb][0] + bs2[ca].x, 0.f);
                    float v1 = fmaxf(acc[ca][nb][1] + bs2[ca].y, 0.f);
                    float v2 = fmaxf(acc[ca][nb][2] + bs2[ca].z, 0.f);
                    float v3 = fmaxf(acc[ca][nb][3] + bs2[ca].w, 0.f);
                    s[nb] += v0 * wo[ca].x + v1 * wo[ca].y + v2 * wo[ca].z + v3 * wo[ca].w;
                }
#pragma unroll
            for (int nb = 0; nb < 4; ++nb) {
                s[nb] += __shfl_xor(s[nb], 16);
                s[nb] += __shfl_xor(s[nb], 32);
            }
            if (lg == 0) {
#pragma unroll
                for (int nb = 0; nb < 4; ++nb) part[w * TM + nb * 16 + lr] = s[nb];
            }
        }

        // L0(e+1) -> hA (register-only inputs; overlaps with dot)
        {
            f32x4 acc0[2][4];
#pragma unroll
            for (int ca = 0; ca < 2; ++ca)
#pragma unroll
                for (int nb = 0; nb < 4; ++nb) {
                    acc0[ca][nb] = (f32x4){0.f, 0.f, 0.f, 0.f};
                    acc0[ca][nb] = __builtin_amdgcn_mfma_f32_16x16x32_bf16(a0[ca], xb[nb], acc0[ca][nb], 0, 0, 0);
                }
            loadA32(W0p + e2 * HD * 32, a0, tc, lr, lg);       // W0(e+2)
            loadA128<0, 2>(W1b + e1 * HD * HD, a1, tc, lr, lg); // W1(e+1) first half
            epi_store(acc0, (char*)hA, bs0, tc, lr, lg);
        }
        bar_lds();

        // fold dot partials (concurrent with next P1's LDS reads; part rewritten only in next P2)
        if (tid < TM)
            bmax = fmaxf(bmax, part[tid] + part[TM + tid] + part[2 * TM + tid] + part[3 * TM + tid] + bo[e]);
    }

    if (tid < TM) out[row0 + tid] = bmax;
}

extern "C" void kernel_launch(void* const* d_in, const int* in_sizes, int n_in,
                              void* d_out, int out_size, void* d_ws, size_t ws_size,
                              hipStream_t stream) {
    const float* coords = (const float*)d_in[0];
    const float* W0 = (const float*)d_in[1];
    const float* b0 = (const float*)d_in[2];
    const float* W1 = (const float*)d_in[3];
    const float* b1 = (const float*)d_in[4];
    const float* W2 = (const float*)d_in[5];
    const float* b2 = (const float*)d_in[6];
    const float* Wo = (const float*)d_in[7];
    const float* bo = (const float*)d_in[8];
    float* out = (float*)d_out;

    char* ws = (char*)d_ws;
    unsigned short* W1b = (unsigned short*)(ws);            // 256 KB
    unsigned short* W2b = (unsigned short*)(ws + 262144);   // 256 KB
    unsigned short* W0p = (unsigned short*)(ws + 524288);   // 64 KB

    prep_kernel<<<dim3(256), dim3(256), 0, stream>>>(
        W0, W1, W2, (unsigned int*)W1b, (unsigned int*)W2b, (unsigned int*)W0p);

    moe_main<<<dim3(NPTS / TM), dim3(256), 0, stream>>>(
        coords, b0, b1, b2, Wo, bo, W0p, W1b, W2b, out);
}

// Round 7
// 85.274 us; speedup vs baseline: 1.2964x; 1.2964x over previous
//
#include <hip/hip_runtime.h>

#define NE 8
#define HD 128
#define NPTS 65536
#define TM 64    // points per tile
#define NT (NPTS / TM)   // 1024 tiles
#define XPS 40   // Xp row stride in shorts (80 B)

typedef __bf16 bf16x8 __attribute__((ext_vector_type(8)));
typedef __bf16 bf16x4 __attribute__((ext_vector_type(4)));
typedef float f32x4 __attribute__((ext_vector_type(4)));

__device__ __forceinline__ unsigned int f2bf(float f) {
    unsigned int u = __float_as_uint(f);
    u += 0x7FFFu + ((u >> 16) & 1u);   // RNE
    return u >> 16;
}

// order-preserving fp32 <-> uint encoding (for atomicMax-based float max)
__device__ __forceinline__ unsigned int fenc(float f) {
    unsigned int u = __float_as_uint(f);
    return ((int)u < 0) ? ~u : (u | 0x80000000u);
}
__device__ __forceinline__ float fdec(unsigned int u) {
    return __uint_as_float(((int)u < 0) ? (u & 0x7FFFFFFFu) : ~u);
}

// XOR swizzle on 256B rows
__device__ __forceinline__ unsigned int swz(int row, int byte_in_row) {
    return (unsigned int)((row * 256 + byte_in_row) ^ ((row & 7) << 4));
}

// LDS-only barrier: drains ds ops but leaves global (vmcnt) loads in flight.
__device__ __forceinline__ void bar_lds() {
    asm volatile("s_waitcnt lgkmcnt(0)\ns_barrier" ::: "memory");
}

__device__ __forceinline__ void loadA128(const unsigned short* __restrict__ Ag,
                                         bf16x8 (&a)[2][4], int tc, int lr, int lg) {
#pragma unroll
    for (int ca = 0; ca < 2; ++ca)
#pragma unroll
        for (int kb = 0; kb < 4; ++kb)
            a[ca][kb] = *(const bf16x8*)(Ag + (tc + ca * 16 + lr) * HD + kb * 32 + lg * 8);
}

// MFMA core over LDS B (swizzled)
__device__ __forceinline__ void gemm_core(const bf16x8 (&a)[2][4], const char* Bb,
                                          f32x4 (&acc)[2][4], int lr, int lg) {
#pragma unroll
    for (int kb = 0; kb < 4; ++kb) {
        bf16x8 b[4];
#pragma unroll
        for (int nb = 0; nb < 4; ++nb)
            b[nb] = *(const bf16x8*)(Bb + swz(nb * 16 + lr, kb * 64 + lg * 16));
#pragma unroll
        for (int ca = 0; ca < 2; ++ca)
#pragma unroll
            for (int nb = 0; nb < 4; ++nb)
                acc[ca][nb] = __builtin_amdgcn_mfma_f32_16x16x32_bf16(a[ca][kb], b[nb], acc[ca][nb], 0, 0, 0);
    }
}

// bias + relu + bf16-pack + swizzled LDS store
__device__ __forceinline__ void epi_store(const f32x4 (&acc)[2][4], char* Db,
                                          const float4 (&bs)[2], int tc, int lr, int lg) {
#pragma unroll
    for (int ca = 0; ca < 2; ++ca) {
        int c0 = tc + ca * 16 + lg * 4;
#pragma unroll
        for (int nb = 0; nb < 4; ++nb) {
            int r = nb * 16 + lr;
            bf16x4 pk;
            pk[0] = (__bf16)fmaxf(acc[ca][nb][0] + bs[ca].x, 0.f);
            pk[1] = (__bf16)fmaxf(acc[ca][nb][1] + bs[ca].y, 0.f);
            pk[2] = (__bf16)fmaxf(acc[ca][nb][2] + bs[ca].z, 0.f);
            pk[3] = (__bf16)fmaxf(acc[ca][nb][3] + bs[ca].w, 0.f);
            *(bf16x4*)(Db + swz(r, c0 * 2)) = pk;
        }
    }
}

// Prep: fp32 -> bf16 weights; W0 padded K:3->32; ALSO init out-encoding to 0 (= -inf).
__global__ void prep_kernel(const float* __restrict__ W0,
                            const float* __restrict__ W1,
                            const float* __restrict__ W2,
                            unsigned int* __restrict__ W1b,
                            unsigned int* __restrict__ W2b,
                            unsigned int* __restrict__ W0p,
                            unsigned int* __restrict__ outenc) {
    int i = blockIdx.x * 256 + threadIdx.x;  // 0..65535
    float2 v = *(const float2*)(W1 + 2 * i);
    W1b[i] = f2bf(v.x) | (f2bf(v.y) << 16);
    float2 u = *(const float2*)(W2 + 2 * i);
    W2b[i] = f2bf(u.x) | (f2bf(u.y) << 16);
    outenc[i] = 0u;   // below enc of any real float
    if (i < NE * HD * 16) {
        int row = i >> 4;
        int kk = (i & 15) * 2;
        float a = (kk < 3) ? W0[row * 3 + kk] : 0.f;
        float b = (kk + 1 < 3) ? W0[row * 3 + kk + 1] : 0.f;
        W0p[i] = f2bf(a) | (f2bf(b) << 16);
    }
}

__global__ void decode_kernel(unsigned int* __restrict__ outenc) {
    int i = blockIdx.x * 256 + threadIdx.x;
    outenc[i] = __float_as_uint(fdec(outenc[i]));
}

// One (tile, expert) per block. 4 barriers total, no loop-carried register chains.
__global__ __launch_bounds__(256, 4) void moe_expert(
    const float* __restrict__ coords,
    const float* __restrict__ b0, const float* __restrict__ b1,
    const float* __restrict__ b2,
    const float* __restrict__ Wo, const float* __restrict__ bo,
    const unsigned short* __restrict__ W0p,
    const unsigned short* __restrict__ W1b,
    const unsigned short* __restrict__ W2b,
    unsigned int* __restrict__ outenc) {
    __shared__ __align__(16) unsigned short hA[TM * HD];   // 16 KB
    __shared__ __align__(16) unsigned short hB[TM * HD];   // 16 KB
    __shared__ __align__(16) unsigned short Xp[TM * XPS];  // 5 KB
    __shared__ __align__(16) float part[4 * TM];           // 1 KB

    const int tid = threadIdx.x;
    const int lane = tid & 63;
    const int w = tid >> 6;
    const int lr = lane & 15;
    const int lg = lane >> 4;
    const int tc = w * 32;
    const int tile = blockIdx.x & (NT - 1);
    const int e = blockIdx.x >> 10;
    const int row0 = tile * TM;

    // issue weight loads ASAP (hide L2 latency under Xp init + barrier)
    bf16x8 a0[2], a1[2][4];
#pragma unroll
    for (int ca = 0; ca < 2; ++ca)
        a0[ca] = *(const bf16x8*)(W0p + e * HD * 32 + (tc + ca * 16 + lr) * 32 + lg * 8);
    loadA128(W1b + e * HD * HD, a1, tc, lr, lg);

    if (tid < TM) {
        unsigned int* rowp = (unsigned int*)(Xp + tid * XPS);
        float c0 = coords[(row0 + tid) * 3 + 0];
        float c1 = coords[(row0 + tid) * 3 + 1];
        float c2 = coords[(row0 + tid) * 3 + 2];
        rowp[0] = f2bf(c0) | (f2bf(c1) << 16);
        rowp[1] = f2bf(c2);
#pragma unroll
        for (int i = 2; i < XPS / 2; ++i) rowp[i] = 0;
    }
    bar_lds();

    // ---- L0: h1 = relu(X*W0^T + b0) -> hA ----
    {
        bf16x8 xb[4];
#pragma unroll
        for (int nb = 0; nb < 4; ++nb)
            xb[nb] = *(const bf16x8*)(Xp + (nb * 16 + lr) * XPS + lg * 8);
        float4 bs0[2];
#pragma unroll
        for (int ca = 0; ca < 2; ++ca) bs0[ca] = *(const float4*)(b0 + e * HD + tc + ca * 16 + lg * 4);
        f32x4 acc[2][4];
#pragma unroll
        for (int ca = 0; ca < 2; ++ca)
#pragma unroll
            for (int nb = 0; nb < 4; ++nb) {
                acc[ca][nb] = (f32x4){0.f, 0.f, 0.f, 0.f};
                acc[ca][nb] = __builtin_amdgcn_mfma_f32_16x16x32_bf16(a0[ca], xb[nb], acc[ca][nb], 0, 0, 0);
            }
        epi_store(acc, (char*)hA, bs0, tc, lr, lg);
    }
    bar_lds();

    // ---- L1: h2 = relu(h1*W1^T + b1) -> hB ----
    bf16x8 a2[2][4];
    loadA128(W2b + e * HD * HD, a2, tc, lr, lg);   // in flight during L1
    {
        float4 bs1[2];
#pragma unroll
        for (int ca = 0; ca < 2; ++ca) bs1[ca] = *(const float4*)(b1 + e * HD + tc + ca * 16 + lg * 4);
        f32x4 acc[2][4];
#pragma unroll
        for (int ca = 0; ca < 2; ++ca)
#pragma unroll
            for (int nb = 0; nb < 4; ++nb) acc[ca][nb] = (f32x4){0.f, 0.f, 0.f, 0.f};
        gemm_core(a1, (const char*)hA, acc, lr, lg);
        epi_store(acc, (char*)hB, bs1, tc, lr, lg);
    }
    bar_lds();

    // ---- L2 + fused dot ----
    {
        float4 bs2[2], wo[2];
#pragma unroll
        for (int ca = 0; ca < 2; ++ca) {
            int c0 = tc + ca * 16 + lg * 4;
            bs2[ca] = *(const float4*)(b2 + e * HD + c0);
            wo[ca] = *(const float4*)(Wo + e * HD + c0);
        }
        f32x4 acc[2][4];
#pragma unroll
        for (int ca = 0; ca < 2; ++ca)
#pragma unroll
            for (int nb = 0; nb < 4; ++nb) acc[ca][nb] = (f32x4){0.f, 0.f, 0.f, 0.f};
        gemm_core(a2, (const char*)hB, acc, lr, lg);

        float s[4] = {0.f, 0.f, 0.f, 0.f};
#pragma unroll
        for (int ca = 0; ca < 2; ++ca)
#pragma unroll
            for (int nb = 0; nb < 4; ++nb) {
                float v0 = fmaxf(acc[ca][nb][0] + bs2[ca].x, 0.f);
                float v1 = fmaxf(acc[ca][nb][1] + bs2[ca].y, 0.f);
                float v2 = fmaxf(acc[ca][nb][2] + bs2[ca].z, 0.f);
                float v3 = fmaxf(acc[ca][nb][3] + bs2[ca].w, 0.f);
                s[nb] += v0 * wo[ca].x + v1 * wo[ca].y + v2 * wo[ca].z + v3 * wo[ca].w;
            }
#pragma unroll
        for (int nb = 0; nb < 4; ++nb) {
            s[nb] += __shfl_xor(s[nb], 16);
            s[nb] += __shfl_xor(s[nb], 32);
        }
        if (lg == 0) {
#pragma unroll
            for (int nb = 0; nb < 4; ++nb) part[w * TM + nb * 16 + lr] = s[nb];
        }
    }
    bar_lds();

    if (tid < TM) {
        float v = part[tid] + part[TM + tid] + part[2 * TM + tid] + part[3 * TM + tid] + bo[e];
        atomicMax(&outenc[row0 + tid], fenc(v));
    }
}

extern "C" void kernel_launch(void* const* d_in, const int* in_sizes, int n_in,
                              void* d_out, int out_size, void* d_ws, size_t ws_size,
                              hipStream_t stream) {
    const float* coords = (const float*)d_in[0];
    const float* W0 = (const float*)d_in[1];
    const float* b0 = (const float*)d_in[2];
    const float* W1 = (const float*)d_in[3];
    const float* b1 = (const float*)d_in[4];
    const float* W2 = (const float*)d_in[5];
    const float* b2 = (const float*)d_in[6];
    const float* Wo = (const float*)d_in[7];
    const float* bo = (const float*)d_in[8];
    unsigned int* outenc = (unsigned int*)d_out;

    char* ws = (char*)d_ws;
    unsigned short* W1b = (unsigned short*)(ws);            // 256 KB
    unsigned short* W2b = (unsigned short*)(ws + 262144);   // 256 KB
    unsigned short* W0p = (unsigned short*)(ws + 524288);   // 64 KB

    prep_kernel<<<dim3(256), dim3(256), 0, stream>>>(
        W0, W1, W2, (unsigned int*)W1b, (unsigned int*)W2b, (unsigned int*)W0p, outenc);

    moe_expert<<<dim3(NT * NE), dim3(256), 0, stream>>>(
        coords, b0, b1, b2, Wo, bo, W0p, W1b, W2b, outenc);

    decode_kernel<<<dim3(NPTS / 256), dim3(256), 0, stream>>>(outenc);
}